// Round 12
// baseline (202.788 us; speedup 1.0000x reference)
//
#include <hip/hip_runtime.h>
#include <math.h>

#define D_MELS 80
#define F4ROW  20          // float4 per row
#define T_DIM  4000
#define NQM    7           // main quantities: 0=l1 1=bandextra 2=diff2 3=tgt2 4=energy 5=delta 6=delta2
#define NTHR   256
#define GPW    4           // consecutive 16-row groups per wave (L1-hot neighborhood)

// ---- DPP helpers (verified working in R11) ----
template<int CTRL>
__device__ __forceinline__ float dppf(float v) {
    return __int_as_float(__builtin_amdgcn_update_dpp(
        0, __float_as_int(v), CTRL, 0xF, 0xF, true));
}
#define ROW_SHL1 0x101
#define ROW_SHL2 0x102
#define ROW_SHL4 0x104
#define ROW_SHL8 0x108

__device__ __forceinline__ float wave_sum(float v) {
    v += dppf<ROW_SHL8>(v);
    v += dppf<ROW_SHL4>(v);
    v += dppf<ROW_SHL2>(v);
    v += dppf<ROW_SHL1>(v);            // lane 0 of each 16-lane row = row sum
    v += __shfl_xor(v, 16, 64);
    v += __shfl_xor(v, 32, 64);        // lane 0 = full wave sum
    return v;
}

// ---------------- flags + mask-count pre-kernel (as R11) ----------------
__global__ __launch_bounds__(NTHR) void mel_flags(
    const float* __restrict__ mask, int* __restrict__ bflag,
    float* __restrict__ cpart, int BT, int nmb, int rowsPerMB, int nfb)
{
    const int tid  = threadIdx.x;
    const int lane = tid & 63;
    const int wv   = tid >> 6;
    const int g    = blockIdx.x * (NTHR / 64) + wv;   // main-block id

    float cm = 0.f, cdm = 0.f, cd2m = 0.f;
    int   fl = 0;

    if (g < nmb) {
        const int rlo = g * rowsPerMB;
        int rhi = rlo + rowsPerMB; if (rhi > BT) rhi = BT;
        for (int r = rlo - 2 + lane; r < rhi; r += 64) {
            if (r < 0) continue;
            float m = mask[r];
            fl |= (m != 0.f);
            if (r >= rlo && m != 0.f) {
                int t = r % T_DIM;
                cm += m;
                if (t >= 1) {
                    float m1 = mask[r - 1];
                    cdm += m * m1;
                    if (t >= 2) cd2m += m * m1 * mask[r - 2];
                }
            }
        }
    }

    const bool anyl = __any(fl != 0);
    #pragma unroll
    for (int off = 32; off > 0; off >>= 1) {
        cm   += __shfl_down(cm,   off, 64);
        cdm  += __shfl_down(cdm,  off, 64);
        cd2m += __shfl_down(cd2m, off, 64);
    }
    if (g < nmb && lane == 0) bflag[g] = anyl ? 1 : 0;

    __shared__ float cred[NTHR / 64][3];
    if (lane == 0) { cred[wv][0] = cm; cred[wv][1] = cdm; cred[wv][2] = cd2m; }
    __syncthreads();
    if (tid < 3) {
        float s = 0.f;
        #pragma unroll
        for (int w2 = 0; w2 < NTHR / 64; ++w2) s += cred[w2][tid];
        cpart[tid * nfb + blockIdx.x] = s;
    }
}

// ---------------- main kernel: copy-shaped contiguous stream ----------------
// Lane l reads float4 #(fb + l + 64k) — wave = 1KB contiguous per load, like
// the 6.3TB/s copy ubench (25 GB/s/CU misses vs our tiled 14). Rows r-1/r-2
// come from plain loads at idx-20/-40: their lines were demand-fetched
// moments ago by this same wave (or its CU neighbors) -> L1 hits, no extra
// line-misses. No __any, no mask->data serialization, no barriers.
__global__ __launch_bounds__(NTHR, 2) void mel_loss_main(
    const float* __restrict__ pred, const float* __restrict__ tgt,
    const float* __restrict__ mask, const int* __restrict__ bflag,
    float* __restrict__ partial, int BT, int ngroups, int nmb)
{
    const int tid = threadIdx.x;

    if (!bflag[blockIdx.x]) {                    // scalar load, uniform branch
        if (tid < NQM) partial[tid * nmb + blockIdx.x] = 0.f;
        return;
    }

    const int lane = tid & 63;
    const int wv   = tid >> 6;

    const float4* p4 = (const float4*)pred;
    const float4* q4 = (const float4*)tgt;
    const long ntot4 = (long)BT * F4ROW;

    // lane-constant per-k geometry: j = lane + 64k, row_off = j/20, dims = 4*(j%20)+c
    int  row_off[5];
    float4 bsel[5];
    #pragma unroll
    for (int k = 0; k < 5; ++k) {
        int j = lane + 64 * k;
        row_off[k] = j / 20;
        int d0 = (j % 20) * 4;
        bsel[k].x = ((unsigned)(d0 + 0 - 10) < 40u) ? 1.f : 0.f;
        bsel[k].y = ((unsigned)(d0 + 1 - 10) < 40u) ? 1.f : 0.f;
        bsel[k].z = ((unsigned)(d0 + 2 - 10) < 40u) ? 1.f : 0.f;
        bsel[k].w = ((unsigned)(d0 + 3 - 10) < 40u) ? 1.f : 0.f;
    }

    __shared__ float rs[NTHR / 64][16];          // per-wave row sums (energy)

    float v_l1 = 0.f, v_frr = 0.f, v_diff2 = 0.f, v_tgt2 = 0.f, v_energy = 0.f;
    float v_d = 0.f, v_d2 = 0.f;

    const int gbase = (blockIdx.x * (NTHR / 64) + wv) * GPW;

    for (int gi = 0; gi < GPW; ++gi) {
        const int g = gbase + gi;
        if (g >= ngroups) break;
        const int  rg = g * 16;                  // base row of group
        const int  tg = rg % T_DIM;              // t of base row (wrap-safe below)
        const long fb = (long)g * 320;           // base float4 index

        if (lane < 16) rs[wv][lane] = 0.f;       // per-wave LDS, same-wave ordered

        // two-deep pipeline, static [k&1] indexing (fully unrolled)
        float4 P[2][3], Q[2][3];
        float  M[2][3];

        #define LOADK(kk, b)                                                      \
        {                                                                         \
            long i0 = fb + lane + 64 * (kk);                                      \
            if (i0 >= ntot4) i0 = ntot4 - 1;                                      \
            long i1 = i0 - 20; if (i1 < 0) i1 = 0;                                \
            long i2 = i0 - 40; if (i2 < 0) i2 = 0;                                \
            P[b][0] = p4[i0]; Q[b][0] = q4[i0];                                   \
            P[b][1] = p4[i1]; Q[b][1] = q4[i1];                                   \
            P[b][2] = p4[i2]; Q[b][2] = q4[i2];                                   \
            int r = rg + row_off[kk]; int rc = r < BT ? r : BT - 1;               \
            int r1 = rc - 1; if (r1 < 0) r1 = 0;                                  \
            int r2 = rc - 2; if (r2 < 0) r2 = 0;                                  \
            M[b][0] = mask[rc]; M[b][1] = mask[r1]; M[b][2] = mask[r2];           \
        }

        LOADK(0, 0)
        #pragma unroll
        for (int k = 0; k < 5; ++k) {
            if (k < 4) {
                if ((k & 1) == 0) LOADK(k + 1, 1)
                else              LOADK(k + 1, 0)
            }
            const int b = k & 1;
            const int r = rg + row_off[k];
            int t = tg + row_off[k]; if (t >= T_DIM) t -= T_DIM;

            float e0 = P[b][0].x - Q[b][0].x, e1 = P[b][0].y - Q[b][0].y,
                  e2 = P[b][0].z - Q[b][0].z, e3 = P[b][0].w - Q[b][0].w;
            float f0 = P[b][1].x - Q[b][1].x, f1 = P[b][1].y - Q[b][1].y,
                  f2 = P[b][1].z - Q[b][1].z, f3 = P[b][1].w - Q[b][1].w;
            float g0 = P[b][2].x - Q[b][2].x, g1 = P[b][2].y - Q[b][2].y,
                  g2 = P[b][2].z - Q[b][2].z, g3 = P[b][2].w - Q[b][2].w;

            const float mt   = (r < BT) ? M[b][0] : 0.f;
            const float dmv  = (t >= 1) ? mt * M[b][1] : 0.f;
            const float d2mv = (t >= 2) ? dmv * M[b][2] : 0.f;

            float a0 = fabsf(e0), a1 = fabsf(e1), a2 = fabsf(e2), a3 = fabsf(e3);
            v_l1    += (a0 + a1 + a2 + a3) * mt;
            v_frr   += (a0 * bsel[k].x + a1 * bsel[k].y
                      + a2 * bsel[k].z + a3 * bsel[k].w) * mt;
            v_diff2 += (e0 * e0 + e1 * e1 + e2 * e2 + e3 * e3) * mt;
            v_tgt2  += (Q[b][0].x * Q[b][0].x + Q[b][0].y * Q[b][0].y
                      + Q[b][0].z * Q[b][0].z + Q[b][0].w * Q[b][0].w) * mt;
            v_d     += (fabsf(e0 - f0) + fabsf(e1 - f1)
                      + fabsf(e2 - f2) + fabsf(e3 - f3)) * dmv;
            v_d2    += (fabsf(e0 - 2.f * f0 + g0) + fabsf(e1 - 2.f * f1 + g1)
                      + fabsf(e2 - 2.f * f2 + g2) + fabsf(e3 - 2.f * f3 + g3)) * d2mv;

            atomicAdd(&rs[wv][row_off[k]], e0 + e1 + e2 + e3);   // ds_add_f32
        }
        #undef LOADK

        // energy finish: |row sum| * mask  (same-wave DS ordering, no barrier)
        if (lane < 16) {
            int r = rg + lane;
            float mm = (r < BT) ? mask[r] : 0.f;
            v_energy += fabsf(rs[wv][lane]) * mm;
        }
    }

    // ---- block reduction ----
    float vals[NQM] = {v_l1, v_frr, v_diff2, v_tgt2, v_energy, v_d, v_d2};
    #pragma unroll
    for (int q = 0; q < NQM; ++q) vals[q] = wave_sum(vals[q]);

    __shared__ float red[NTHR / 64][NQM];
    if (lane == 0) {
        #pragma unroll
        for (int q = 0; q < NQM; ++q) red[wv][q] = vals[q];
    }
    __syncthreads();
    if (tid < NQM) {
        float s = 0.f;
        #pragma unroll
        for (int w2 = 0; w2 < NTHR / 64; ++w2) s += red[w2][tid];
        partial[tid * nmb + blockIdx.x] = s;
    }
}

// ---------------- finalize (as R11) ----------------
__global__ __launch_bounds__(640) void mel_loss_finalize(
    const float* __restrict__ partial, const float* __restrict__ cpart,
    const float* __restrict__ w, float* __restrict__ out, int nmb, int nfb)
{
    const int tid = threadIdx.x;
    const int wv  = tid >> 6;        // 0..6 main quantities; 7..9 mask counts
    const int lane = tid & 63;
    __shared__ float fin[10];

    float s = 0.f;
    if (wv < NQM) {
        for (int i = lane; i < nmb; i += 64) s += partial[wv * nmb + i];
    } else {
        for (int i = lane; i < nfb; i += 64) s += cpart[(wv - NQM) * nfb + i];
    }
    #pragma unroll
    for (int off = 32; off > 0; off >>= 1) s += __shfl_down(s, off, 64);
    if (lane == 0 && wv < 10) fin[wv] = s;
    __syncthreads();

    if (tid == 0) {
        float l1s = fin[0], frrs = fin[1], diff2 = fin[2], tgt2 = fin[3];
        float energys = fin[4], ds = fin[5], d2s = fin[6];
        float ms = fin[7], dms = fin[8], d2ms = fin[9];

        float wsum = 0.f;
        for (int d = 0; d < D_MELS; ++d) wsum += w[d];
        float wmean = wsum / (float)D_MELS;

        float n1  = fmaxf(ms   * (float)D_MELS, 1.f);
        float nd  = fmaxf(dms  * (float)D_MELS, 1.f);
        float nd2 = fmaxf(d2ms * (float)D_MELS, 1.f);

        float l1_loss     = l1s / n1;
        float delta_loss  = ds / nd;
        float delta2_loss = d2s / nd2;
        float sc_num = sqrtf(diff2 / n1);
        float sc_den = fmaxf(sqrtf(tgt2 / n1), 1e-8f);
        float sc_loss = sc_num / sc_den;
        float band_loss = ((l1s + frrs) / n1) / wmean;
        float energy_loss = (energys / (float)D_MELS) / fmaxf(ms, 1.f);

        out[0] = 1.0f * l1_loss + 0.5f * delta_loss + 0.25f * delta2_loss
               + 0.5f * sc_loss + 1.0f * band_loss + 0.5f * energy_loss;
    }
}

extern "C" void kernel_launch(void* const* d_in, const int* in_sizes, int n_in,
                              void* d_out, int out_size, void* d_ws, size_t ws_size,
                              hipStream_t stream) {
    const float* pred = (const float*)d_in[0];
    const float* tgt  = (const float*)d_in[1];
    const float* mask = (const float*)d_in[2];
    const float* w    = (const float*)d_in[3];
    int BT = in_sizes[2];                         // B*T = 256000

    int ngroups = (BT + 15) / 16;                 // 16000 16-row groups
    int wavesN  = (ngroups + GPW - 1) / GPW;      // 4000
    int nmb     = (wavesN + (NTHR / 64) - 1) / (NTHR / 64);   // 1000 main blocks
    int nfb     = (nmb + (NTHR / 64) - 1) / (NTHR / 64);
    int rowsPerMB = (NTHR / 64) * GPW * 16;       // 256 contiguous rows per block

    float* partial = (float*)d_ws;                // NQM*nmb
    float* cpart   = partial + NQM * nmb;         // 3*nfb
    int*   bflag   = (int*)(cpart + 3 * nfb);     // nmb

    mel_flags<<<nfb, NTHR, 0, stream>>>(mask, bflag, cpart, BT, nmb, rowsPerMB, nfb);
    mel_loss_main<<<nmb, NTHR, 0, stream>>>(pred, tgt, mask, bflag, partial, BT, ngroups, nmb);
    mel_loss_finalize<<<1, 640, 0, stream>>>(partial, cpart, w, (float*)d_out, nmb, nfb);
}